// Round 7
// baseline (421.225 us; speedup 1.0000x reference)
//
#include <hip/hip_runtime.h>
#include <hip/hip_bf16.h>

typedef __hip_bfloat16 bf16;

#define N_NODES 100000
#define N_EDGES 3200000
#define N_GRAPHS 512
#define NBKT    ((N_NODES + 255) / 256)               // 391 buckets of 256 nodes
#define CAP     10496                                 // slots per bucket window (8-aligned)
#define EPB     8192                                  // edges per k_bucket block
#define NBLK_A  ((N_EDGES + EPB - 1) / EPB)           // 391
#define FP8_SCALE 64.0f
#define FP8_INV   (1.0f / 64.0f)

// ---------- fp8 e4m3 helpers (OCP on gfx950) ----------

__device__ inline unsigned char f32_to_fp8(float v) {
#if __has_builtin(__builtin_amdgcn_cvt_pk_fp8_f32)
    return (unsigned char)(__builtin_amdgcn_cvt_pk_fp8_f32(v, v, 0, 0) & 0xFF);
#else
    unsigned u = __float_as_uint(v);
    unsigned s = (u >> 24) & 0x80;
    float a = fabsf(v);
    if (a < 9.765625e-4f) return (unsigned char)s;
    if (a >= 448.f) return (unsigned char)(s | 0x7E);
    if (a < 0.015625f) {
        int mm = (int)(a * 512.f + 0.5f);
        if (mm > 7) mm = 7;
        return (unsigned char)(s | mm);
    }
    unsigned keep = (u >> 20) & 1;
    u = (u & 0x7FFFFFFF) + 0x7FFFF + keep;
    unsigned e = ((u >> 23) & 0xFF) - 120;
    if (e > 15) { e = 15; return (unsigned char)(s | 0x7E); }
    return (unsigned char)(s | (e << 3) | ((u >> 20) & 7));
#endif
}

// pack 4 f32 -> 4 fp8 in one dword
__device__ inline unsigned pack4_fp8(float o0, float o1, float o2, float o3) {
#if __has_builtin(__builtin_amdgcn_cvt_pk_fp8_f32)
    unsigned d = 0;
    d = (unsigned)__builtin_amdgcn_cvt_pk_fp8_f32(o0, o1, (int)d, 0);
    d = (unsigned)__builtin_amdgcn_cvt_pk_fp8_f32(o2, o3, (int)d, 1);
    return d;
#else
    return (unsigned)f32_to_fp8(o0) | ((unsigned)f32_to_fp8(o1) << 8) |
           ((unsigned)f32_to_fp8(o2) << 16) | ((unsigned)f32_to_fp8(o3) << 24);
#endif
}

__device__ inline float fp8_to_f32(unsigned int b) {
    unsigned s = (b >> 7) & 1, e = (b >> 3) & 15, m = b & 7;
    float v = (e == 0) ? (float)m * 0.001953125f
                       : __uint_as_float(((e + 120u) << 23) | (m << 20));
    return s ? -v : v;
}

// accumulate 4 packed fp8 into a[0..3]
__device__ inline void acc4(float* a, unsigned v) {
#if __has_builtin(__builtin_amdgcn_cvt_pk_f32_fp8)
    typedef float f32x2 __attribute__((ext_vector_type(2)));
    f32x2 lo = __builtin_amdgcn_cvt_pk_f32_fp8((int)v, false);
    f32x2 hi = __builtin_amdgcn_cvt_pk_f32_fp8((int)v, true);
    a[0] += lo.x; a[1] += lo.y; a[2] += hi.x; a[3] += hi.y;
#elif __has_builtin(__builtin_amdgcn_cvt_f32_fp8)
    a[0] += __builtin_amdgcn_cvt_f32_fp8(v, 0);
    a[1] += __builtin_amdgcn_cvt_f32_fp8(v, 1);
    a[2] += __builtin_amdgcn_cvt_f32_fp8(v, 2);
    a[3] += __builtin_amdgcn_cvt_f32_fp8(v, 3);
#else
    a[0] += fp8_to_f32(v & 0xFF);
    a[1] += fp8_to_f32((v >> 8) & 0xFF);
    a[2] += fp8_to_f32((v >> 16) & 0xFF);
    a[3] += fp8_to_f32((v >> 24) & 0xFF);
#endif
}

__device__ inline unsigned short f2bf(float x) {
    unsigned u = __float_as_uint(x);
    return (unsigned short)((u + 0x7FFF + ((u >> 16) & 1)) >> 16);
}

// ---------- init per-bucket cursors to window bases ----------

__global__ void k_ginit(int* __restrict__ gcur) {
    int b = blockIdx.x * blockDim.x + threadIdx.x;
    if (b < NBKT) gcur[b] = b * CAP;
}

// ---------- Pass A: bin edges by dst>>8 into fixed-CAP bucket windows ----------
// Record = (s<<8) | (d&255)

__global__ void __launch_bounds__(256) k_bucket(const int* __restrict__ ei,
                                                int* __restrict__ gcur,
                                                int* __restrict__ ebuf) {
    __shared__ int cnt[NBKT];
    __shared__ int base[NBKT];
    int t = threadIdx.x;
    for (int i = t; i < NBKT; i += 256) cnt[i] = 0;
    __syncthreads();
    int e0 = blockIdx.x * EPB + t;
    int sv[32], dv[32];
    #pragma unroll
    for (int j = 0; j < 32; ++j) {
        int e = e0 + j * 256;
        if (e < N_EDGES) {
            sv[j] = ei[e];
            dv[j] = ei[N_EDGES + e];
            atomicAdd(&cnt[dv[j] >> 8], 1);
        } else dv[j] = -1;
    }
    __syncthreads();
    for (int i = t; i < NBKT; i += 256) {
        base[i] = atomicAdd(&gcur[i], cnt[i]);
        cnt[i] = 0;
    }
    __syncthreads();
    #pragma unroll
    for (int j = 0; j < 32; ++j) {
        if (dv[j] >= 0) {
            int b = dv[j] >> 8;
            int r = atomicAdd(&cnt[b], 1);
            ebuf[base[b] + r] = (sv[j] << 8) | (dv[j] & 255);
        }
    }
}

// ---------- Pass B: per-bucket: deg histogram -> rc/dis, 8-aligned segments,
//            dummy-padded col window, LDS-cursor scatter ----------

__global__ void __launch_bounds__(256) k_fill2(const int* __restrict__ ebuf,
                                               const int* __restrict__ gcur,
                                               int2* __restrict__ rc,
                                               float* __restrict__ dis,
                                               int* __restrict__ col) {
    __shared__ int cnt[256];
    __shared__ int sc[256];
    __shared__ int exs[256];
    __shared__ int cur[256];
    int b = blockIdx.x, t = threadIdx.x;
    int n0 = b * 256;
    int nrec = gcur[b] - b * CAP;
    const int* eb = ebuf + (size_t)b * CAP;
    int* cw = col + (size_t)b * CAP;
    cnt[t] = 0; cur[t] = 0;
    __syncthreads();
    for (int i = t; i < nrec; i += 256)
        atomicAdd(&cnt[eb[i] & 255], 1);
    __syncthreads();
    int c0 = cnt[t];
    int a8 = (c0 + 7) & ~7;          // 8-aligned segment size
    sc[t] = a8; __syncthreads();
    for (int off = 1; off < 256; off <<= 1) {   // inclusive scan
        int u = (t >= off) ? sc[t - off] : 0;
        __syncthreads();
        sc[t] += u;
        __syncthreads();
    }
    int myex = sc[t] - a8;           // exclusive
    exs[t] = myex;
    int n = n0 + t;
    if (n < N_NODES) {
        rc[n] = make_int2(b * CAP + myex, c0);
        dis[n] = rsqrtf((float)(c0 + 1));        // +1 self-loop
    }
    // fill whole window with dummy row index, then scatter real cols over it
    for (int i = t; i < CAP; i += 256) cw[i] = N_NODES;
    __syncthreads();
    for (int i = t; i < nrec; i += 256) {
        int rec = eb[i];
        int dl = rec & 255;
        cw[exs[dl] + atomicAdd(&cur[dl], 1)] = rec >> 8;
    }
}

// ---------- folded embedding weight: Wc = W_emb@W1, bc = b_emb@W1 ----------

__global__ void k_wc(const float* __restrict__ W_emb, const float* __restrict__ b_emb,
                     const float* __restrict__ W1, float* __restrict__ Wc,
                     float* __restrict__ bc) {
    int t = threadIdx.x;
    for (int i = t; i < 32 * 64; i += 256) {
        int a = i / 64, b = i % 64;
        float acc = 0.f;
        for (int k = 0; k < 64; ++k) acc += W_emb[a * 64 + k] * W1[k * 64 + b];
        Wc[i] = acc;
    }
    if (t < 64) {
        float acc = 0.f;
        for (int k = 0; k < 64; ++k) acc += b_emb[k] * W1[k * 64 + t];
        bc[t] = acc;
    }
}

// ---------- layer-1 matmul -> split fp8 half-tables ----------

__global__ void __launch_bounds__(256) k_mm1(const float* __restrict__ inp,
                                             const float* __restrict__ W,
                                             const float* __restrict__ bias,
                                             const float* __restrict__ dis,
                                             unsigned char* __restrict__ tA,
                                             unsigned char* __restrict__ tB) {
    __shared__ float Wl[32][64];
    __shared__ float hs[16][32];
    int t = threadIdx.x;
    for (int i = t; i < 32 * 64; i += 256) Wl[i / 64][i % 64] = W[i];
    int row0 = blockIdx.x * 16;
    for (int i = t; i < 16 * 32; i += 256) {
        int r = row0 + i / 32, k = i % 32;
        hs[i / 32][k] = inp[(size_t)r * 32 + k];
    }
    __syncthreads();
    int c = t & 63, rg = t >> 6;
    float a0 = 0, a1 = 0, a2 = 0, a3 = 0;
    #pragma unroll 4
    for (int k = 0; k < 32; ++k) {
        float wv = Wl[k][c];
        a0 += hs[rg * 4 + 0][k] * wv;
        a1 += hs[rg * 4 + 1][k] * wv;
        a2 += hs[rg * 4 + 2][k] * wv;
        a3 += hs[rg * 4 + 3][k] * wv;
    }
    float bv = bias[c];
    int r = row0 + rg * 4;
    unsigned char* dst = (c < 32) ? tA : tB;
    int cc = c & 31;
    dst[(size_t)(r + 0) * 32 + cc] = f32_to_fp8(FP8_SCALE * dis[r + 0] * (a0 + bv));
    dst[(size_t)(r + 1) * 32 + cc] = f32_to_fp8(FP8_SCALE * dis[r + 1] * (a1 + bv));
    dst[(size_t)(r + 2) * 32 + cc] = f32_to_fp8(FP8_SCALE * dis[r + 2] * (a2 + bv));
    dst[(size_t)(r + 3) * 32 + cc] = f32_to_fp8(FP8_SCALE * dis[r + 3] * (a3 + bv));
}

// ---------- AGG over one 3.2MB half-table (L2-resident per XCD) ----------
// agg[row, 32 feats] = tph[row] + sum_e tph[col[e]]   (bf16 out)

__global__ void __launch_bounds__(256) k_agg(const unsigned* __restrict__ tph,
                                             const int2* __restrict__ rc,
                                             const int* __restrict__ col,
                                             unsigned short* __restrict__ agg) {
    int row = blockIdx.x * 32 + (threadIdx.x >> 3);   // 32 rows/block, exact grid
    int sl = threadIdx.x & 7;                          // 8 lanes/row, dword each
    float a[4] = {0.f, 0.f, 0.f, 0.f};
    acc4(a, tph[(size_t)row * 8 + sl]);                // self-loop term
    int2 r = rc[row];
    int deg8 = (r.y + 7) & ~7;
    const int* cp = col + r.x;
    for (int p = 0; p < deg8; p += 8) {
        int4 ca = *(const int4*)(cp + p);
        int4 cb = *(const int4*)(cp + p + 4);
        unsigned v0 = tph[(size_t)ca.x * 8 + sl];
        unsigned v1 = tph[(size_t)ca.y * 8 + sl];
        unsigned v2 = tph[(size_t)ca.z * 8 + sl];
        unsigned v3 = tph[(size_t)ca.w * 8 + sl];
        unsigned v4 = tph[(size_t)cb.x * 8 + sl];
        unsigned v5 = tph[(size_t)cb.y * 8 + sl];
        unsigned v6 = tph[(size_t)cb.z * 8 + sl];
        unsigned v7 = tph[(size_t)cb.w * 8 + sl];
        acc4(a, v0); acc4(a, v1); acc4(a, v2); acc4(a, v3);
        acc4(a, v4); acc4(a, v5); acc4(a, v6); acc4(a, v7);
    }
    ushort4 o;
    o.x = f2bf(a[0]); o.y = f2bf(a[1]); o.z = f2bf(a[2]); o.w = f2bf(a[3]);
    *(ushort4*)(agg + (size_t)row * 32 + sl * 4) = o;
}

// ---------- COMBINE: h = relu(dis/S*agg + b); !LAST: next halves = fp8(S*dis*(h@Wn)) ----------

template<bool LAST>
__global__ void __launch_bounds__(256) k_comb(const unsigned short* __restrict__ aggA,
                                              const unsigned short* __restrict__ aggB,
                                              const float* __restrict__ dis,
                                              const float* __restrict__ bias,
                                              const float* __restrict__ Wn,
                                              unsigned* __restrict__ tA,
                                              unsigned* __restrict__ tB,
                                              unsigned short* __restrict__ h) {
    __shared__ float Wl[64][64];
    int t = threadIdx.x;
    if (!LAST) {
        for (int i = t; i < 4096; i += 256) Wl[i >> 6][i & 63] = Wn[i];
        __syncthreads();
    }
    int row = blockIdx.x * 16 + (t >> 4);
    int sl = t & 15;
    int slh = sl & 7;
    const unsigned short* ag = (sl < 8) ? aggA : aggB;
    ushort4 av = *(const ushort4*)(ag + (size_t)row * 32 + slh * 4);
    float s = dis[row] * FP8_INV;
    float h0 = fmaxf(s * __uint_as_float((unsigned)av.x << 16) + bias[sl * 4 + 0], 0.f);
    float h1 = fmaxf(s * __uint_as_float((unsigned)av.y << 16) + bias[sl * 4 + 1], 0.f);
    float h2 = fmaxf(s * __uint_as_float((unsigned)av.z << 16) + bias[sl * 4 + 2], 0.f);
    float h3 = fmaxf(s * __uint_as_float((unsigned)av.w << 16) + bias[sl * 4 + 3], 0.f);
    if (LAST) {
        ushort4 hv;
        hv.x = f2bf(h0); hv.y = f2bf(h1); hv.z = f2bf(h2); hv.w = f2bf(h3);
        *(ushort4*)(h + (size_t)row * 64 + sl * 4) = hv;
    } else {
        float o0 = 0.f, o1 = 0.f, o2 = 0.f, o3 = 0.f;
        int wb = t & 48;                         // 16-lane group base within wave
        #pragma unroll
        for (int kk = 0; kk < 16; ++kk) {
            int src = wb + kk;
            float b0 = __shfl(h0, src);
            float b1 = __shfl(h1, src);
            float b2 = __shfl(h2, src);
            float b3 = __shfl(h3, src);
            float4 w0 = *(const float4*)&Wl[4 * kk + 0][sl * 4];
            float4 w1 = *(const float4*)&Wl[4 * kk + 1][sl * 4];
            float4 w2 = *(const float4*)&Wl[4 * kk + 2][sl * 4];
            float4 w3 = *(const float4*)&Wl[4 * kk + 3][sl * 4];
            o0 += b0 * w0.x + b1 * w1.x + b2 * w2.x + b3 * w3.x;
            o1 += b0 * w0.y + b1 * w1.y + b2 * w2.y + b3 * w3.y;
            o2 += b0 * w0.z + b1 * w1.z + b2 * w2.z + b3 * w3.z;
            o3 += b0 * w0.w + b1 * w1.w + b2 * w2.w + b3 * w3.w;
        }
        float sc2 = FP8_SCALE * dis[row];
        unsigned* dst = (sl < 8) ? tA : tB;
        dst[(size_t)row * 8 + slh] = pack4_fp8(sc2 * o0, sc2 * o1, sc2 * o2, sc2 * o3);
    }
}

// ---------- global mean pool: one block per graph, batch sorted ----------

__global__ void __launch_bounds__(256) k_pool(const unsigned short* __restrict__ h,
                                              const int* __restrict__ batch,
                                              float* __restrict__ pooled) {
    __shared__ float part[4][64];
    __shared__ int seg[2];
    int g = blockIdx.x, t = threadIdx.x;
    if (t < 2) {
        int key = g + t;
        int lo = 0, hi = N_NODES;
        while (lo < hi) { int m = (lo + hi) >> 1; if (batch[m] < key) lo = m + 1; else hi = m; }
        seg[t] = lo;
    }
    __syncthreads();
    int start = seg[0], end = seg[1];
    int w = t >> 6, grp = (t >> 4) & 3, sl = t & 15;
    float a[4] = {0.f, 0.f, 0.f, 0.f};
    for (int r = start + w * 4 + grp; r < end; r += 16) {
        ushort4 v = *(const ushort4*)(h + (size_t)r * 64 + sl * 4);
        a[0] += __uint_as_float((unsigned)v.x << 16);
        a[1] += __uint_as_float((unsigned)v.y << 16);
        a[2] += __uint_as_float((unsigned)v.z << 16);
        a[3] += __uint_as_float((unsigned)v.w << 16);
    }
    #pragma unroll
    for (int j = 0; j < 4; ++j) {
        a[j] += __shfl_xor(a[j], 16);
        a[j] += __shfl_xor(a[j], 32);
    }
    if (sl == (t & 63)) {
        #pragma unroll
        for (int j = 0; j < 4; ++j) part[w][sl * 4 + j] = a[j];
    }
    __syncthreads();
    if (t < 64) {
        float s = part[0][t] + part[1][t] + part[2][t] + part[3][t];
        float c = fmaxf((float)(end - start), 1.f);
        pooled[g * 64 + t] = s / c;
    }
}

// ---------- readout MLP + log_softmax ----------

__global__ void k_head(const float* __restrict__ pooled,
                       const float* __restrict__ Wr1, const float* __restrict__ br1,
                       const float* __restrict__ Wr2, const float* __restrict__ br2,
                       const float* __restrict__ Wr3, const float* __restrict__ br3,
                       float* __restrict__ out) {
    int g = blockIdx.x, t = threadIdx.x;  // 64 threads
    __shared__ float p[64], r1[32], r2[16], lg[10];
    p[t] = pooled[g * 64 + t];
    __syncthreads();
    if (t < 32) {
        float a = br1[t];
        for (int k = 0; k < 64; ++k) a += p[k] * Wr1[k * 32 + t];
        r1[t] = fmaxf(a, 0.f);
    }
    __syncthreads();
    if (t < 16) {
        float a = br2[t];
        for (int k = 0; k < 32; ++k) a += r1[k] * Wr2[k * 16 + t];
        r2[t] = fmaxf(a, 0.f);
    }
    __syncthreads();
    if (t < 10) {
        float a = br3[t];
        for (int k = 0; k < 16; ++k) a += r2[k] * Wr3[k * 10 + t];
        lg[t] = a;
    }
    __syncthreads();
    if (t < 10) {
        float m = -1e30f;
        for (int j = 0; j < 10; ++j) m = fmaxf(m, lg[j]);
        float s = 0.f;
        for (int j = 0; j < 10; ++j) s += expf(lg[j] - m);
        out[g * 10 + t] = lg[t] - m - logf(s);
    }
}

extern "C" void kernel_launch(void* const* d_in, const int* in_sizes, int n_in,
                              void* d_out, int out_size, void* d_ws, size_t ws_size,
                              hipStream_t stream) {
    const float* x     = (const float*)d_in[0];
    const int*   ei    = (const int*)d_in[1];
    const int*   batch = (const int*)d_in[2];
    const float* W_emb = (const float*)d_in[4];
    const float* b_emb = (const float*)d_in[5];
    const float* W1    = (const float*)d_in[6];
    const float* b1    = (const float*)d_in[7];
    const float* W2    = (const float*)d_in[8];
    const float* b2    = (const float*)d_in[9];
    const float* W3    = (const float*)d_in[10];
    const float* b3    = (const float*)d_in[11];
    const float* W4    = (const float*)d_in[12];
    const float* b4    = (const float*)d_in[13];
    const float* Wr1   = (const float*)d_in[14];
    const float* br1   = (const float*)d_in[15];
    const float* Wr2   = (const float*)d_in[16];
    const float* br2   = (const float*)d_in[17];
    const float* Wr3   = (const float*)d_in[18];
    const float* br3   = (const float*)d_in[19];
    float* out = (float*)d_out;

    char* ws = (char*)d_ws;
    size_t off = 0;
    auto alloc = [&](size_t b) { char* p = ws + off; off += (b + 511) & ~(size_t)511; return p; };
    size_t TBYTES = (size_t)(N_NODES + 1) * 32;
    int*   col    = (int*)  alloc((size_t)NBKT * CAP * 4);     // 16.4 MB
    char*  ebufh  =         alloc((size_t)NBKT * CAP * 4);     // ebuf, later reused as h
    unsigned char* T0a = (unsigned char*)alloc(TBYTES);        // fp8 half-tables (+dummy row)
    unsigned char* T0b = (unsigned char*)alloc(TBYTES);
    unsigned char* T1a = (unsigned char*)alloc(TBYTES);
    unsigned char* T1b = (unsigned char*)alloc(TBYTES);
    unsigned short* aggA = (unsigned short*)alloc((size_t)N_NODES * 32 * 2);  // bf16
    unsigned short* aggB = (unsigned short*)alloc((size_t)N_NODES * 32 * 2);
    int2*  rc     = (int2*) alloc((size_t)N_NODES * 8);
    float* dis    = (float*)alloc((size_t)N_NODES * 4);
    int*   gcur   = (int*)  alloc((size_t)NBKT * 4);
    float* Wc     = (float*)alloc(32 * 64 * 4);
    float* bc     = (float*)alloc(64 * 4);
    float* pooled = (float*)alloc((size_t)N_GRAPHS * 64 * 4);

    int* ebuf = (int*)ebufh;
    unsigned short* hbuf = (unsigned short*)ebufh;   // alias: h lives where ebuf was

    // zero the dummy gather row (index N_NODES) of all four half-tables
    hipMemsetAsync(T0a + (size_t)N_NODES * 32, 0, 32, stream);
    hipMemsetAsync(T0b + (size_t)N_NODES * 32, 0, 32, stream);
    hipMemsetAsync(T1a + (size_t)N_NODES * 32, 0, 32, stream);
    hipMemsetAsync(T1b + (size_t)N_NODES * 32, 0, 32, stream);

    k_ginit<<<(NBKT + 255) / 256, 256, 0, stream>>>(gcur);
    k_bucket<<<NBLK_A, 256, 0, stream>>>(ei, gcur, ebuf);
    k_fill2<<<NBKT, 256, 0, stream>>>(ebuf, gcur, rc, dis, col);
    k_wc<<<1, 256, 0, stream>>>(W_emb, b_emb, W1, Wc, bc);

    int nbm = N_NODES / 16;   // 6250, exact
    int nba = N_NODES / 32;   // 3125, exact

    k_mm1<<<nbm, 256, 0, stream>>>(x, Wc, bc, dis, T0a, T0b);

    const float* lb[4] = {b1, b2, b3, b4};
    const float* lw[4] = {W2, W3, W4, nullptr};
    unsigned char* cura = T0a; unsigned char* curb = T0b;
    unsigned char* nxta = T1a; unsigned char* nxtb = T1b;
    for (int l = 0; l < 4; ++l) {
        k_agg<<<nba, 256, 0, stream>>>((const unsigned*)cura, rc, col, aggA);
        k_agg<<<nba, 256, 0, stream>>>((const unsigned*)curb, rc, col, aggB);
        if (l < 3) {
            k_comb<false><<<nbm, 256, 0, stream>>>(aggA, aggB, dis, lb[l], lw[l],
                                                   (unsigned*)nxta, (unsigned*)nxtb, nullptr);
            unsigned char* ta = cura; cura = nxta; nxta = ta;
            unsigned char* tb = curb; curb = nxtb; nxtb = tb;
        } else {
            k_comb<true><<<nbm, 256, 0, stream>>>(aggA, aggB, dis, lb[l], nullptr,
                                                  nullptr, nullptr, hbuf);
        }
    }

    k_pool<<<N_GRAPHS, 256, 0, stream>>>(hbuf, batch, pooled);
    k_head<<<N_GRAPHS, 64, 0, stream>>>(pooled, Wr1, br1, Wr2, br2, Wr3, br3, out);
}

// Round 8
// 361.648 us; speedup vs baseline: 1.1647x; 1.1647x over previous
//
#include <hip/hip_runtime.h>
#include <hip/hip_bf16.h>

typedef __hip_bfloat16 bf16;
typedef short bf16x8 __attribute__((ext_vector_type(8)));
typedef float f32x4 __attribute__((ext_vector_type(4)));

#define N_NODES 100000
#define N_EDGES 3200000
#define N_GRAPHS 512
#define NBKT    ((N_NODES + 255) / 256)               // 391 buckets of 256 nodes
#define CAP     10496                                 // slots per bucket window (8-aligned)
#define EPB     4096                                  // edges per k_bucket block
#define NBLK_A  ((N_EDGES + EPB - 1) / EPB)           // 782
#define FP8_SCALE 64.0f
#define FP8_INV   (1.0f / 64.0f)

// ---------- fp8 e4m3 helpers (OCP on gfx950) ----------

__device__ inline unsigned char f32_to_fp8(float v) {
#if __has_builtin(__builtin_amdgcn_cvt_pk_fp8_f32)
    return (unsigned char)(__builtin_amdgcn_cvt_pk_fp8_f32(v, v, 0, 0) & 0xFF);
#else
    unsigned u = __float_as_uint(v);
    unsigned s = (u >> 24) & 0x80;
    float a = fabsf(v);
    if (a < 9.765625e-4f) return (unsigned char)s;
    if (a >= 448.f) return (unsigned char)(s | 0x7E);
    if (a < 0.015625f) {
        int mm = (int)(a * 512.f + 0.5f);
        if (mm > 7) mm = 7;
        return (unsigned char)(s | mm);
    }
    unsigned keep = (u >> 20) & 1;
    u = (u & 0x7FFFFFFF) + 0x7FFFF + keep;
    unsigned e = ((u >> 23) & 0xFF) - 120;
    if (e > 15) { e = 15; return (unsigned char)(s | 0x7E); }
    return (unsigned char)(s | (e << 3) | ((u >> 20) & 7));
#endif
}

__device__ inline unsigned pack4_fp8(float o0, float o1, float o2, float o3) {
#if __has_builtin(__builtin_amdgcn_cvt_pk_fp8_f32)
    unsigned d = 0;
    d = (unsigned)__builtin_amdgcn_cvt_pk_fp8_f32(o0, o1, (int)d, 0);
    d = (unsigned)__builtin_amdgcn_cvt_pk_fp8_f32(o2, o3, (int)d, 1);
    return d;
#else
    return (unsigned)f32_to_fp8(o0) | ((unsigned)f32_to_fp8(o1) << 8) |
           ((unsigned)f32_to_fp8(o2) << 16) | ((unsigned)f32_to_fp8(o3) << 24);
#endif
}

__device__ inline float fp8_to_f32(unsigned int b) {
    unsigned s = (b >> 7) & 1, e = (b >> 3) & 15, m = b & 7;
    float v = (e == 0) ? (float)m * 0.001953125f
                       : __uint_as_float(((e + 120u) << 23) | (m << 20));
    return s ? -v : v;
}

__device__ inline void acc4(float* a, unsigned v) {
#if __has_builtin(__builtin_amdgcn_cvt_pk_f32_fp8)
    typedef float f32x2 __attribute__((ext_vector_type(2)));
    f32x2 lo = __builtin_amdgcn_cvt_pk_f32_fp8((int)v, false);
    f32x2 hi = __builtin_amdgcn_cvt_pk_f32_fp8((int)v, true);
    a[0] += lo.x; a[1] += lo.y; a[2] += hi.x; a[3] += hi.y;
#elif __has_builtin(__builtin_amdgcn_cvt_f32_fp8)
    a[0] += __builtin_amdgcn_cvt_f32_fp8(v, 0);
    a[1] += __builtin_amdgcn_cvt_f32_fp8(v, 1);
    a[2] += __builtin_amdgcn_cvt_f32_fp8(v, 2);
    a[3] += __builtin_amdgcn_cvt_f32_fp8(v, 3);
#else
    a[0] += fp8_to_f32(v & 0xFF);
    a[1] += fp8_to_f32((v >> 8) & 0xFF);
    a[2] += fp8_to_f32((v >> 16) & 0xFF);
    a[3] += fp8_to_f32((v >> 24) & 0xFF);
#endif
}

__device__ inline unsigned short f2bf(float x) {
    unsigned u = __float_as_uint(x);
    return (unsigned short)((u + 0x7FFF + ((u >> 16) & 1)) >> 16);
}

// ---------- init per-bucket cursors to window bases ----------

__global__ void k_ginit(int* __restrict__ gcur) {
    int b = blockIdx.x * blockDim.x + threadIdx.x;
    if (b < NBKT) gcur[b] = b * CAP;
}

// ---------- Pass A: bin edges by dst>>8 into fixed-CAP bucket windows ----------

__global__ void __launch_bounds__(256) k_bucket(const int* __restrict__ ei,
                                                int* __restrict__ gcur,
                                                int* __restrict__ ebuf) {
    __shared__ int cnt[NBKT];
    __shared__ int base[NBKT];
    int t = threadIdx.x;
    for (int i = t; i < NBKT; i += 256) cnt[i] = 0;
    __syncthreads();
    int e0 = blockIdx.x * EPB + t;
    int sv[16], dv[16];
    #pragma unroll
    for (int j = 0; j < 16; ++j) {
        int e = e0 + j * 256;
        if (e < N_EDGES) {
            sv[j] = ei[e];
            dv[j] = ei[N_EDGES + e];
            atomicAdd(&cnt[dv[j] >> 8], 1);
        } else dv[j] = -1;
    }
    __syncthreads();
    for (int i = t; i < NBKT; i += 256) {
        base[i] = atomicAdd(&gcur[i], cnt[i]);
        cnt[i] = 0;
    }
    __syncthreads();
    #pragma unroll
    for (int j = 0; j < 16; ++j) {
        if (dv[j] >= 0) {
            int b = dv[j] >> 8;
            int r = atomicAdd(&cnt[b], 1);
            ebuf[base[b] + r] = (sv[j] << 8) | (dv[j] & 255);
        }
    }
}

// ---------- Pass B: per-bucket histogram -> rc/dis, 8-aligned dummy-padded col ----------

__global__ void __launch_bounds__(256) k_fill2(const int* __restrict__ ebuf,
                                               const int* __restrict__ gcur,
                                               int2* __restrict__ rc,
                                               float* __restrict__ dis,
                                               int* __restrict__ col) {
    __shared__ int cnt[256];
    __shared__ int sc[256];
    __shared__ int exs[256];
    __shared__ int cur[256];
    __shared__ int tot;
    int b = blockIdx.x, t = threadIdx.x;
    int n0 = b * 256;
    int nrec = gcur[b] - b * CAP;
    const int* eb = ebuf + (size_t)b * CAP;
    int* cw = col + (size_t)b * CAP;
    cnt[t] = 0; cur[t] = 0;
    __syncthreads();
    for (int i = t; i < nrec; i += 256)
        atomicAdd(&cnt[eb[i] & 255], 1);
    __syncthreads();
    int c0 = cnt[t];
    int a8 = (c0 + 7) & ~7;
    sc[t] = a8; __syncthreads();
    for (int off = 1; off < 256; off <<= 1) {
        int u = (t >= off) ? sc[t - off] : 0;
        __syncthreads();
        sc[t] += u;
        __syncthreads();
    }
    int myex = sc[t] - a8;
    exs[t] = myex;
    if (t == 255) tot = sc[255];
    int n = n0 + t;
    if (n < N_NODES) {
        rc[n] = make_int2(b * CAP + myex, c0);
        dis[n] = rsqrtf((float)(c0 + 1));
    }
    __syncthreads();
    for (int i = t; i < tot; i += 256) cw[i] = N_NODES;   // dummy-fill used window
    __syncthreads();
    for (int i = t; i < nrec; i += 256) {
        int rec = eb[i];
        int dl = rec & 255;
        cw[exs[dl] + atomicAdd(&cur[dl], 1)] = rec >> 8;
    }
}

// ---------- folded embedding weight: Wc = W_emb@W1, bc = b_emb@W1 ----------

__global__ void k_wc(const float* __restrict__ W_emb, const float* __restrict__ b_emb,
                     const float* __restrict__ W1, float* __restrict__ Wc,
                     float* __restrict__ bc) {
    int t = threadIdx.x;
    for (int i = t; i < 32 * 64; i += 256) {
        int a = i / 64, b = i % 64;
        float acc = 0.f;
        for (int k = 0; k < 64; ++k) acc += W_emb[a * 64 + k] * W1[k * 64 + b];
        Wc[i] = acc;
    }
    if (t < 64) {
        float acc = 0.f;
        for (int k = 0; k < 64; ++k) acc += b_emb[k] * W1[k * 64 + t];
        bc[t] = acc;
    }
}

// ---------- Wn -> per-lane MFMA A-fragment layout (A = Wn^T), bf16 ----------
// Wfrag[layer][ (kt*4+mt)*64 + lane ][ j ] = bf16( Wn[k][m] ),
//   m = mt*16 + (lane&15), k = kt*32 + (lane>>4)*8 + j

__global__ void k_wprep(const float* __restrict__ W2, const float* __restrict__ W3,
                        const float* __restrict__ W4, unsigned short* __restrict__ Wfrag) {
    const float* W = (blockIdx.x == 0) ? W2 : (blockIdx.x == 1) ? W3 : W4;
    unsigned short* dst = Wfrag + (size_t)blockIdx.x * 4096;
    int t = threadIdx.x;
    for (int i = 0; i < 16; ++i) {
        int flat = t * 16 + i;
        int j = flat & 7, lane = (flat >> 3) & 63, mt = (flat >> 9) & 3, kt = flat >> 11;
        int m = mt * 16 + (lane & 15);
        int k = kt * 32 + ((lane >> 4) << 3) + j;
        dst[flat] = f2bf(W[k * 64 + m]);
    }
}

// ---------- layer-1 matmul -> split fp8 half-tables ----------

__global__ void __launch_bounds__(256) k_mm1(const float* __restrict__ inp,
                                             const float* __restrict__ W,
                                             const float* __restrict__ bias,
                                             const float* __restrict__ dis,
                                             unsigned char* __restrict__ tA,
                                             unsigned char* __restrict__ tB) {
    __shared__ float Wl[32][64];
    __shared__ float hs[16][32];
    int t = threadIdx.x;
    for (int i = t; i < 32 * 64; i += 256) Wl[i / 64][i % 64] = W[i];
    int row0 = blockIdx.x * 16;
    for (int i = t; i < 16 * 32; i += 256) {
        int r = row0 + i / 32, k = i % 32;
        hs[i / 32][k] = inp[(size_t)r * 32 + k];
    }
    __syncthreads();
    int c = t & 63, rg = t >> 6;
    float a0 = 0, a1 = 0, a2 = 0, a3 = 0;
    #pragma unroll 4
    for (int k = 0; k < 32; ++k) {
        float wv = Wl[k][c];
        a0 += hs[rg * 4 + 0][k] * wv;
        a1 += hs[rg * 4 + 1][k] * wv;
        a2 += hs[rg * 4 + 2][k] * wv;
        a3 += hs[rg * 4 + 3][k] * wv;
    }
    float bv = bias[c];
    int r = row0 + rg * 4;
    unsigned char* dst = (c < 32) ? tA : tB;
    int cc = c & 31;
    dst[(size_t)(r + 0) * 32 + cc] = f32_to_fp8(FP8_SCALE * dis[r + 0] * (a0 + bv));
    dst[(size_t)(r + 1) * 32 + cc] = f32_to_fp8(FP8_SCALE * dis[r + 1] * (a1 + bv));
    dst[(size_t)(r + 2) * 32 + cc] = f32_to_fp8(FP8_SCALE * dis[r + 2] * (a2 + bv));
    dst[(size_t)(r + 3) * 32 + cc] = f32_to_fp8(FP8_SCALE * dis[r + 3] * (a3 + bv));
}

// ---------- AGG over one 3.2MB half-table (L2-resident) ----------

__global__ void __launch_bounds__(256) k_agg(const unsigned* __restrict__ tph,
                                             const int2* __restrict__ rc,
                                             const int* __restrict__ col,
                                             unsigned short* __restrict__ agg) {
    int row = blockIdx.x * 32 + (threadIdx.x >> 3);
    int sl = threadIdx.x & 7;
    float a[4] = {0.f, 0.f, 0.f, 0.f};
    float b[4] = {0.f, 0.f, 0.f, 0.f};
    acc4(a, tph[(size_t)row * 8 + sl]);                // self-loop term
    int2 r = rc[row];
    int deg8 = (r.y + 7) & ~7;
    const int* cp = col + r.x;
    for (int p = 0; p < deg8; p += 8) {
        int4 ca = *(const int4*)(cp + p);
        int4 cb = *(const int4*)(cp + p + 4);
        unsigned v0 = tph[(size_t)ca.x * 8 + sl];
        unsigned v1 = tph[(size_t)ca.y * 8 + sl];
        unsigned v2 = tph[(size_t)ca.z * 8 + sl];
        unsigned v3 = tph[(size_t)ca.w * 8 + sl];
        unsigned v4 = tph[(size_t)cb.x * 8 + sl];
        unsigned v5 = tph[(size_t)cb.y * 8 + sl];
        unsigned v6 = tph[(size_t)cb.z * 8 + sl];
        unsigned v7 = tph[(size_t)cb.w * 8 + sl];
        acc4(a, v0); acc4(b, v1); acc4(a, v2); acc4(b, v3);
        acc4(a, v4); acc4(b, v5); acc4(a, v6); acc4(b, v7);
    }
    ushort4 o;
    o.x = f2bf(a[0] + b[0]); o.y = f2bf(a[1] + b[1]);
    o.z = f2bf(a[2] + b[2]); o.w = f2bf(a[3] + b[3]);
    *(ushort4*)(agg + (size_t)row * 32 + sl * 4) = o;
}

// ---------- MFMA COMBINE: h = relu(dis/S*agg + b); next halves = fp8(S*dis*(h@Wn)) ----------
// 64 rows/block, 4 waves; wave w owns rows [w*16, w*16+16).
// D = A*B with A = Wn^T (M=out-col), B = h^T-ish (N=row)  =>  lane gets 4 consecutive cols.

__global__ void __launch_bounds__(256) k_combm(const unsigned short* __restrict__ aggA,
                                               const unsigned short* __restrict__ aggB,
                                               const float* __restrict__ dis,
                                               const float* __restrict__ bias,
                                               const unsigned short* __restrict__ Wfrag,
                                               unsigned* __restrict__ tA,
                                               unsigned* __restrict__ tB) {
    __shared__ unsigned short h_lds[64][72];          // bf16, padded stride
    int t = threadIdx.x;
    int rowbase = blockIdx.x * 64;
    {
        int row = t >> 2, q = t & 3;
        int grow = rowbase + row;
        if (grow < N_NODES) {
            float f = dis[grow] * FP8_INV;
            #pragma unroll
            for (int i = 0; i < 4; ++i) {
                int c0 = q * 16 + i * 4;
                const unsigned short* src = ((c0 < 32) ? aggA : aggB) +
                                            (size_t)grow * 32 + (c0 & 31);
                ushort4 v = *(const ushort4*)src;
                short4 o;
                o.x = (short)f2bf(fmaxf(f * __uint_as_float((unsigned)v.x << 16) + bias[c0 + 0], 0.f));
                o.y = (short)f2bf(fmaxf(f * __uint_as_float((unsigned)v.y << 16) + bias[c0 + 1], 0.f));
                o.z = (short)f2bf(fmaxf(f * __uint_as_float((unsigned)v.z << 16) + bias[c0 + 2], 0.f));
                o.w = (short)f2bf(fmaxf(f * __uint_as_float((unsigned)v.w << 16) + bias[c0 + 3], 0.f));
                *(short4*)&h_lds[row][c0] = o;
            }
        } else {
            #pragma unroll
            for (int i = 0; i < 4; ++i)
                *(short4*)&h_lds[row][q * 16 + i * 4] = make_short4(0, 0, 0, 0);
        }
    }
    __syncthreads();
    int w = t >> 6, l = t & 63;
    f32x4 acc[4] = {{0,0,0,0}, {0,0,0,0}, {0,0,0,0}, {0,0,0,0}};
    const bf16x8* wf = (const bf16x8*)Wfrag;
    #pragma unroll
    for (int kt = 0; kt < 2; ++kt) {
        bf16x8 bfr = *(const bf16x8*)&h_lds[w * 16 + (l & 15)][kt * 32 + ((l >> 4) << 3)];
        #pragma unroll
        for (int mt = 0; mt < 4; ++mt) {
            bf16x8 afr = wf[(kt * 4 + mt) * 64 + l];
            acc[mt] = __builtin_amdgcn_mfma_f32_16x16x32_bf16(afr, bfr, acc[mt], 0, 0, 0);
        }
    }
    int hrow = rowbase + w * 16 + (l & 15);
    if (hrow < N_NODES) {
        float sc2 = FP8_SCALE * dis[hrow];
        #pragma unroll
        for (int mt = 0; mt < 4; ++mt) {
            int colbase = mt * 16 + ((l >> 4) << 2);
            unsigned d = pack4_fp8(sc2 * acc[mt][0], sc2 * acc[mt][1],
                                   sc2 * acc[mt][2], sc2 * acc[mt][3]);
            if (colbase < 32) tA[(size_t)hrow * 8 + (colbase >> 2)] = d;
            else              tB[(size_t)hrow * 8 + ((colbase - 32) >> 2)] = d;
        }
    }
}

// ---------- last-layer combine: h (bf16) only ----------

__global__ void __launch_bounds__(256) k_combl(const unsigned short* __restrict__ aggA,
                                               const unsigned short* __restrict__ aggB,
                                               const float* __restrict__ dis,
                                               const float* __restrict__ bias,
                                               unsigned short* __restrict__ h) {
    int t = threadIdx.x;
    int row = blockIdx.x * 16 + (t >> 4);
    int sl = t & 15;
    int slh = sl & 7;
    const unsigned short* ag = (sl < 8) ? aggA : aggB;
    ushort4 av = *(const ushort4*)(ag + (size_t)row * 32 + slh * 4);
    float s = dis[row] * FP8_INV;
    ushort4 hv;
    hv.x = f2bf(fmaxf(s * __uint_as_float((unsigned)av.x << 16) + bias[sl * 4 + 0], 0.f));
    hv.y = f2bf(fmaxf(s * __uint_as_float((unsigned)av.y << 16) + bias[sl * 4 + 1], 0.f));
    hv.z = f2bf(fmaxf(s * __uint_as_float((unsigned)av.z << 16) + bias[sl * 4 + 2], 0.f));
    hv.w = f2bf(fmaxf(s * __uint_as_float((unsigned)av.w << 16) + bias[sl * 4 + 3], 0.f));
    *(ushort4*)(h + (size_t)row * 64 + sl * 4) = hv;
}

// ---------- global mean pool: one block per graph, batch sorted ----------

__global__ void __launch_bounds__(256) k_pool(const unsigned short* __restrict__ h,
                                              const int* __restrict__ batch,
                                              float* __restrict__ pooled) {
    __shared__ float part[4][64];
    __shared__ int seg[2];
    int g = blockIdx.x, t = threadIdx.x;
    if (t < 2) {
        int key = g + t;
        int lo = 0, hi = N_NODES;
        while (lo < hi) { int m = (lo + hi) >> 1; if (batch[m] < key) lo = m + 1; else hi = m; }
        seg[t] = lo;
    }
    __syncthreads();
    int start = seg[0], end = seg[1];
    int w = t >> 6, grp = (t >> 4) & 3, sl = t & 15;
    float a[4] = {0.f, 0.f, 0.f, 0.f};
    for (int r = start + w * 4 + grp; r < end; r += 16) {
        ushort4 v = *(const ushort4*)(h + (size_t)r * 64 + sl * 4);
        a[0] += __uint_as_float((unsigned)v.x << 16);
        a[1] += __uint_as_float((unsigned)v.y << 16);
        a[2] += __uint_as_float((unsigned)v.z << 16);
        a[3] += __uint_as_float((unsigned)v.w << 16);
    }
    #pragma unroll
    for (int j = 0; j < 4; ++j) {
        a[j] += __shfl_xor(a[j], 16);
        a[j] += __shfl_xor(a[j], 32);
    }
    if (sl == (t & 63)) {
        #pragma unroll
        for (int j = 0; j < 4; ++j) part[w][sl * 4 + j] = a[j];
    }
    __syncthreads();
    if (t < 64) {
        float s = part[0][t] + part[1][t] + part[2][t] + part[3][t];
        float c = fmaxf((float)(end - start), 1.f);
        pooled[g * 64 + t] = s / c;
    }
}

// ---------- readout MLP + log_softmax ----------

__global__ void k_head(const float* __restrict__ pooled,
                       const float* __restrict__ Wr1, const float* __restrict__ br1,
                       const float* __restrict__ Wr2, const float* __restrict__ br2,
                       const float* __restrict__ Wr3, const float* __restrict__ br3,
                       float* __restrict__ out) {
    int g = blockIdx.x, t = threadIdx.x;  // 64 threads
    __shared__ float p[64], r1[32], r2[16], lg[10];
    p[t] = pooled[g * 64 + t];
    __syncthreads();
    if (t < 32) {
        float a = br1[t];
        for (int k = 0; k < 64; ++k) a += p[k] * Wr1[k * 32 + t];
        r1[t] = fmaxf(a, 0.f);
    }
    __syncthreads();
    if (t < 16) {
        float a = br2[t];
        for (int k = 0; k < 32; ++k) a += r1[k] * Wr2[k * 16 + t];
        r2[t] = fmaxf(a, 0.f);
    }
    __syncthreads();
    if (t < 10) {
        float a = br3[t];
        for (int k = 0; k < 16; ++k) a += r2[k] * Wr3[k * 10 + t];
        lg[t] = a;
    }
    __syncthreads();
    if (t < 10) {
        float m = -1e30f;
        for (int j = 0; j < 10; ++j) m = fmaxf(m, lg[j]);
        float s = 0.f;
        for (int j = 0; j < 10; ++j) s += expf(lg[j] - m);
        out[g * 10 + t] = lg[t] - m - logf(s);
    }
}

extern "C" void kernel_launch(void* const* d_in, const int* in_sizes, int n_in,
                              void* d_out, int out_size, void* d_ws, size_t ws_size,
                              hipStream_t stream) {
    const float* x     = (const float*)d_in[0];
    const int*   ei    = (const int*)d_in[1];
    const int*   batch = (const int*)d_in[2];
    const float* W_emb = (const float*)d_in[4];
    const float* b_emb = (const float*)d_in[5];
    const float* W1    = (const float*)d_in[6];
    const float* b1    = (const float*)d_in[7];
    const float* W2    = (const float*)d_in[8];
    const float* b2    = (const float*)d_in[9];
    const float* W3    = (const float*)d_in[10];
    const float* b3    = (const float*)d_in[11];
    const float* W4    = (const float*)d_in[12];
    const float* b4    = (const float*)d_in[13];
    const float* Wr1   = (const float*)d_in[14];
    const float* br1   = (const float*)d_in[15];
    const float* Wr2   = (const float*)d_in[16];
    const float* br2   = (const float*)d_in[17];
    const float* Wr3   = (const float*)d_in[18];
    const float* br3   = (const float*)d_in[19];
    float* out = (float*)d_out;

    char* ws = (char*)d_ws;
    size_t off = 0;
    auto alloc = [&](size_t b) { char* p = ws + off; off += (b + 511) & ~(size_t)511; return p; };
    size_t TBYTES = (size_t)(N_NODES + 1) * 32;
    int*   col    = (int*)  alloc((size_t)NBKT * CAP * 4);     // 16.4 MB
    char*  ebufh  =         alloc((size_t)NBKT * CAP * 4);     // ebuf, later reused as h
    unsigned char* T0a = (unsigned char*)alloc(TBYTES);        // fp8 half-tables (+dummy row)
    unsigned char* T0b = (unsigned char*)alloc(TBYTES);
    unsigned char* T1a = (unsigned char*)alloc(TBYTES);
    unsigned char* T1b = (unsigned char*)alloc(TBYTES);
    unsigned short* aggA = (unsigned short*)alloc((size_t)N_NODES * 32 * 2);  // bf16
    unsigned short* aggB = (unsigned short*)alloc((size_t)N_NODES * 32 * 2);
    int2*  rc     = (int2*) alloc((size_t)N_NODES * 8);
    float* dis    = (float*)alloc((size_t)N_NODES * 4);
    int*   gcur   = (int*)  alloc((size_t)NBKT * 4);
    float* Wc     = (float*)alloc(32 * 64 * 4);
    float* bc     = (float*)alloc(64 * 4);
    unsigned short* Wfrag = (unsigned short*)alloc(3 * 4096 * 2);
    float* pooled = (float*)alloc((size_t)N_GRAPHS * 64 * 4);

    int* ebuf = (int*)ebufh;
    unsigned short* hbuf = (unsigned short*)ebufh;   // alias: h lives where ebuf was

    hipMemsetAsync(T0a + (size_t)N_NODES * 32, 0, 32, stream);
    hipMemsetAsync(T0b + (size_t)N_NODES * 32, 0, 32, stream);
    hipMemsetAsync(T1a + (size_t)N_NODES * 32, 0, 32, stream);
    hipMemsetAsync(T1b + (size_t)N_NODES * 32, 0, 32, stream);

    k_ginit<<<(NBKT + 255) / 256, 256, 0, stream>>>(gcur);
    k_bucket<<<NBLK_A, 256, 0, stream>>>(ei, gcur, ebuf);
    k_fill2<<<NBKT, 256, 0, stream>>>(ebuf, gcur, rc, dis, col);
    k_wc<<<1, 256, 0, stream>>>(W_emb, b_emb, W1, Wc, bc);
    k_wprep<<<3, 256, 0, stream>>>(W2, W3, W4, Wfrag);

    int nbm = N_NODES / 16;        // 6250
    int nba = N_NODES / 32;        // 3125
    int nbc = (N_NODES + 63) / 64; // 1563

    k_mm1<<<nbm, 256, 0, stream>>>(x, Wc, bc, dis, T0a, T0b);

    const float* lb[4] = {b1, b2, b3, b4};
    unsigned char* cura = T0a; unsigned char* curb = T0b;
    unsigned char* nxta = T1a; unsigned char* nxtb = T1b;
    for (int l = 0; l < 4; ++l) {
        k_agg<<<nba, 256, 0, stream>>>((const unsigned*)cura, rc, col, aggA);
        k_agg<<<nba, 256, 0, stream>>>((const unsigned*)curb, rc, col, aggB);
        if (l < 3) {
            k_combm<<<nbc, 256, 0, stream>>>(aggA, aggB, dis, lb[l], Wfrag + (size_t)l * 4096,
                                             (unsigned*)nxta, (unsigned*)nxtb);
            unsigned char* ta = cura; cura = nxta; nxta = ta;
            unsigned char* tb = curb; curb = nxtb; nxtb = tb;
        } else {
            k_combl<<<nbm, 256, 0, stream>>>(aggA, aggB, dis, lb[l], hbuf);
        }
    }

    k_pool<<<N_GRAPHS, 256, 0, stream>>>(hbuf, batch, pooled);
    k_head<<<N_GRAPHS, 64, 0, stream>>>(pooled, Wr1, br1, Wr2, br2, Wr3, br3, out);
}